// Round 1
// baseline (281.657 us; speedup 1.0000x reference)
//
#include <hip/hip_runtime.h>

typedef unsigned short u16;
typedef unsigned char u8;
typedef __attribute__((ext_vector_type(8))) short short8;
typedef __attribute__((ext_vector_type(2))) float f32x2;
typedef __attribute__((ext_vector_type(4))) float f32x4;
typedef __attribute__((ext_vector_type(4))) unsigned short us4;
typedef __attribute__((ext_vector_type(8))) unsigned short us8;
typedef __attribute__((ext_vector_type(4))) unsigned int u32x4;

#define N_NODES 50000
#define N_EDGES 800000
#define DIM 128
#define NINV (1.0f / 50000.0f)
#define SROW 136      /* LDS row stride (u16) */
#define NBKT 3125     /* node groups of 16: 50000/16 */
#define CAP 512       /* bucket capacity; mean fill 256, P(overflow) ~ e^-99 */

__device__ __forceinline__ float bf2f(u16 u) {
    union { unsigned int i; float f; } v; v.i = ((unsigned int)u) << 16; return v.f;
}
__device__ __forceinline__ u16 f2bf(float f) {
    union { float f; unsigned int i; } v; v.f = f;
    return (u16)((v.i + 0x7FFFu + ((v.i >> 16) & 1u)) >> 16);
}

// ---------------- prep: pack B1/B2, split x, single-pass edge bucketing ----------------
// blocks 0..15: pack B1; 16..31: pack B2; 32..32+splitB-1: split x;
// rest (3125): one pass over edges, append (src<<4 | dst&15) to bucket[dst>>4].
__global__ __launch_bounds__(256) void k_prep(
        const float* __restrict__ W1l, const float* __restrict__ W1r, u16* __restrict__ Bp1,
        const float* __restrict__ W2l, const float* __restrict__ W2r, u16* __restrict__ Bp2,
        const float* __restrict__ x, u16* __restrict__ xh, u8* __restrict__ xf8,
        const int* __restrict__ esrc, const int* __restrict__ edst,
        int* __restrict__ bcnt, unsigned* __restrict__ bucket, int splitB) {
    int b = blockIdx.x;
    if (b < 32) {
        const float* Wl = (b < 16) ? W1l : W2l;
        const float* Wr = (b < 16) ? W1r : W2r;
        u16* Bp = (b < 16) ? Bp1 : Bp2;
        int idx = (b & 15) * 256 + threadIdx.x;      // 0..4095
        int lane = idx & 63;
        int kc = (idx >> 6) & 7;
        int nt = idx >> 9;
        int q = lane >> 4, nn = lane & 15;
        int col = nt * 16 + nn;
        #pragma unroll
        for (int j = 0; j < 8; ++j) {
            int k = kc * 32 + q * 8 + j;
            float v = (k < 128) ? Wl[k * 128 + col] : Wr[(k - 128) * 128 + col];
            Bp[(long)idx * 8 + j] = f2bf(v);
        }
    } else if (b < 32 + splitB) {
        long i4 = ((long)(b - 32) * 256 + threadIdx.x) * 4;
        f32x4 v = *(const f32x4*)(x + i4);
        us4 h;
        #pragma unroll
        for (int j = 0; j < 4; ++j) h[j] = f2bf(v[j]);
        *(us4*)(xh + i4) = h;
        int p = __builtin_amdgcn_cvt_pk_fp8_f32(v[0], v[1], 0, false);
        p = __builtin_amdgcn_cvt_pk_fp8_f32(v[2], v[3], p, true);
        *(int*)(xf8 + i4) = p;
    } else {
        int e = (b - 32 - splitB) * 256 + threadIdx.x;
        if (e < N_EDGES) {
            int d = edst[e];
            int s = esrc[e];
            int key = d >> 4;
            int pos = atomicAdd(&bcnt[key], 1);
            if (pos < CAP)
                bucket[(long)key * CAP + pos] = ((unsigned)s << 4) | (unsigned)(d & 15);
        }
    }
}

// decode 16 fp8 + (optional BN+relu) + accumulate
template<int BN>
__device__ __forceinline__ void acc_row16(u32x4 w,
        float sum[16], const float av[16], const float ov[16]) {
    float t[16];
    f32x2 p;
    #pragma unroll
    for (int h = 0; h < 4; ++h) {
        p = __builtin_amdgcn_cvt_pk_f32_fp8((int)w[h], false); t[h*4+0] = p[0]; t[h*4+1] = p[1];
        p = __builtin_amdgcn_cvt_pk_f32_fp8((int)w[h], true);  t[h*4+2] = p[0]; t[h*4+3] = p[1];
    }
    #pragma unroll
    for (int k = 0; k < 16; ++k) {
        float v = t[k];
        if (BN) { v = v * av[k] + ov[k]; v = v > 0.f ? v : 0.f; }
        sum[k] += v;
    }
}

// ---------------- fused AGG + GEMM + BN stats (512 threads) ----------------
// phase 0: LDS counting-sort of this block's bucket (hist == degree, indices land in LDS)
// phase 1: gather-mean, 32 lanes/node = 4 edge-quarters x 8 dim-groups
// phase 2: 8 waves, one 16-col MFMA tile each
template<int BN, int W8>
__global__ __launch_bounds__(512) void k_ag(
        const u8* __restrict__ fq, const u16* __restrict__ fh,
        const int* __restrict__ bcnt, const unsigned* __restrict__ bucket,
        const u16* __restrict__ Bph, const float* __restrict__ bias,
        const float* __restrict__ statsPrev, const float* __restrict__ gP,
        const float* __restrict__ btP,
        u16* __restrict__ h16, u8* __restrict__ h8, float* __restrict__ stats) {
    __shared__ u16 sA[16 * SROW];
    __shared__ float acS[256];
    __shared__ u16 sSort[CAP];
    __shared__ int sHist[16];
    __shared__ int sStart[16];
    __shared__ int sCur[16];
    int tid = threadIdx.x;
    long nodebase = (long)blockIdx.x * 16;       // 3125*16 == 50000 exact

    if (BN) {
        if (tid < 128) {
            float s = 0.f, qq = 0.f;
            #pragma unroll
            for (int b = 0; b < 8; ++b) {
                s  += statsPrev[b * 512 + tid];
                qq += statsPrev[b * 512 + 256 + tid];
            }
            float mu = s * NINV;
            float var = qq * NINV - mu * mu;
            float a = gP[tid] * rsqrtf(var + 1e-5f);
            acS[tid] = a;
            acS[128 + tid] = btP[tid] - mu * a;
        }
    }

    // ---- phase 0: stage bucket + LDS counting sort by node-low4 ----
    int cnt = bcnt[blockIdx.x];
    if (cnt > CAP) cnt = CAP;
    bool has = (tid < cnt);
    unsigned ent = 0u;
    if (has) ent = bucket[(long)blockIdx.x * CAP + tid];
    if (tid < 16) sHist[tid] = 0;
    __syncthreads();
    if (has) atomicAdd(&sHist[ent & 15u], 1);
    __syncthreads();
    if (tid == 0) {
        int acc = 0;
        #pragma unroll
        for (int i = 0; i < 16; ++i) { sStart[i] = acc; sCur[i] = acc; acc += sHist[i]; }
    }
    __syncthreads();
    if (has) {
        int p = atomicAdd(&sCur[ent & 15u], 1);
        sSort[p] = (u16)(ent >> 4);
    }
    __syncthreads();

    // ---- phase 1: gather-mean (fp8, 16B/lane, 4-way contiguous edge split) ----
    {
        int grp = tid >> 5;          // node 0..15
        int s5  = tid & 31;
        int sub = s5 >> 3;           // edge quarter 0..3
        int d16 = (s5 & 7) * 16;     // dim base
        int deg = sHist[grp];
        int st  = sStart[grp];
        int qn  = (deg + 3) >> 2;
        int js  = st + sub * qn;
        int je  = js + qn;
        int lim = st + deg;
        if (je > lim) je = lim;
        if (js > lim) js = lim;
        float av[16], ov[16];
        if (BN) {
            #pragma unroll
            for (int k = 0; k < 16; ++k) { av[k] = acS[d16 + k]; ov[k] = acS[128 + d16 + k]; }
        }
        float sum[16];
        #pragma unroll
        for (int k = 0; k < 16; ++k) sum[k] = 0.f;
        int j = js;
        for (; j + 3 < je; j += 4) {
            int i0 = sSort[j], i1 = sSort[j + 1], i2 = sSort[j + 2], i3 = sSort[j + 3];
            u32x4 w0 = *(const u32x4*)(fq + (long)i0 * DIM + d16);
            u32x4 w1 = *(const u32x4*)(fq + (long)i1 * DIM + d16);
            u32x4 w2 = *(const u32x4*)(fq + (long)i2 * DIM + d16);
            u32x4 w3 = *(const u32x4*)(fq + (long)i3 * DIM + d16);
            acc_row16<BN>(w0, sum, av, ov);
            acc_row16<BN>(w1, sum, av, ov);
            acc_row16<BN>(w2, sum, av, ov);
            acc_row16<BN>(w3, sum, av, ov);
        }
        for (; j < je; ++j) {
            int i0 = sSort[j];
            u32x4 w0 = *(const u32x4*)(fq + (long)i0 * DIM + d16);
            acc_row16<BN>(w0, sum, av, ov);
        }
        // combine 4 quarters (xor 8 and 16 stay within the node's 32 lanes)
        #pragma unroll
        for (int k = 0; k < 16; ++k) {
            sum[k] += __shfl_xor(sum[k], 8);
            sum[k] += __shfl_xor(sum[k], 16);
        }
        if (sub == 0) {
            float dn = (deg > 0) ? 1.f / (float)deg : 1.f;
            us8 r0, r1;
            #pragma unroll
            for (int k = 0; k < 8; ++k) {
                r0[k] = f2bf(sum[k] * dn);
                r1[k] = f2bf(sum[8 + k] * dn);
            }
            *(us8*)(sA + grp * SROW + d16) = r0;
            *(us8*)(sA + grp * SROW + d16 + 8) = r1;
        }
    }
    __syncthreads();

    // ---- phase 2: MFMA, 8 waves x one 16-col tile ----
    int cg = tid >> 6, lane = tid & 63;
    int q = lane >> 4, nn = lane & 15;
    long rc = nodebase + nn;

    short8 ah[8];
    #pragma unroll
    for (int kc = 0; kc < 4; ++kc)
        ah[kc] = *(const short8*)(sA + nn * SROW + kc * 32 + q * 8);
    #pragma unroll
    for (int kc = 0; kc < 4; ++kc) {
        int ko = kc * 32 + q * 8;
        us8 rv = *(const us8*)(fh + rc * DIM + ko);
        short8 t;
        if (BN) {
            #pragma unroll
            for (int j = 0; j < 8; ++j) {
                float v = bf2f(rv[j]) * acS[ko + j] + acS[128 + ko + j];
                t[j] = (short)f2bf(v > 0.f ? v : 0.f);
            }
        } else {
            #pragma unroll
            for (int j = 0; j < 8; ++j) t[j] = (short)rv[j];
        }
        ah[4 + kc] = t;
    }

    f32x4 acc = (f32x4){0.f, 0.f, 0.f, 0.f};
    #pragma unroll
    for (int kc = 0; kc < 8; ++kc) {
        short8 bh = *(const short8*)(Bph + (((cg * 8 + kc) * 64 + lane) << 3));
        acc = __builtin_amdgcn_mfma_f32_16x16x32_bf16(ah[kc], bh, acc, 0, 0, 0);
    }

    int bank = blockIdx.x & 7;
    int col = cg * 16 + nn;
    float bv = bias[col];
    float ps = 0.f, pq = 0.f;
    #pragma unroll
    for (int r = 0; r < 4; ++r) {
        float v = acc[r] + bv;
        long idx = (nodebase + q * 4 + r) * DIM + col;
        h16[idx] = f2bf(v);
        if (W8) {
            int pb = __builtin_amdgcn_cvt_pk_fp8_f32(v, v, 0, false);
            h8[idx] = (u8)(pb & 0xff);
        }
        ps += v; pq += v * v;
    }
    ps += __shfl_xor(ps, 16);
    ps += __shfl_xor(ps, 32);
    pq += __shfl_xor(pq, 16);
    pq += __shfl_xor(pq, 32);
    if (q == 0) {
        atomicAdd(&stats[bank * 512 + col], ps);
        atomicAdd(&stats[bank * 512 + 256 + col], pq);
    }
}

// out = relu(bn(h)+x); coeffs computed in-block from banked stats
__global__ __launch_bounds__(256) void k_bn_add_relu(
        const u16* __restrict__ h, const float* __restrict__ stats,
        const float* __restrict__ g, const float* __restrict__ bt,
        const float* __restrict__ x, float* __restrict__ outv) {
    __shared__ float acS[256];
    int tid = threadIdx.x;
    if (tid < 128) {
        float s = 0.f, qq = 0.f;
        #pragma unroll
        for (int b = 0; b < 8; ++b) {
            s  += stats[b * 512 + tid];
            qq += stats[b * 512 + 256 + tid];
        }
        float mu = s * NINV;
        float var = qq * NINV - mu * mu;
        float a = g[tid] * rsqrtf(var + 1e-5f);
        acS[tid] = a;
        acS[128 + tid] = bt[tid] - mu * a;
    }
    __syncthreads();
    long i8 = ((long)blockIdx.x * 256 + tid) * 8;
    int c = (int)(i8 & 127);
    us8 hv = *(const us8*)(h + i8);
    f32x4 x0 = *(const f32x4*)(x + i8);
    f32x4 x1 = *(const f32x4*)(x + i8 + 4);
    f32x4 r0, r1;
    #pragma unroll
    for (int j = 0; j < 4; ++j) {
        float v = bf2f(hv[j]) * acS[c + j] + acS[128 + c + j] + x0[j];
        r0[j] = v > 0.f ? v : 0.f;
        float w = bf2f(hv[4 + j]) * acS[c + 4 + j] + acS[128 + c + 4 + j] + x1[j];
        r1[j] = w > 0.f ? w : 0.f;
    }
    *(f32x4*)(outv + i8) = r0;
    *(f32x4*)(outv + i8 + 4) = r1;
}

extern "C" void kernel_launch(void* const* d_in, const int* in_sizes, int n_in,
                              void* d_out, int out_size, void* d_ws, size_t ws_size,
                              hipStream_t stream) {
    (void)in_sizes; (void)n_in; (void)out_size; (void)ws_size;
    const float* x   = (const float*)d_in[0];
    const int*   ei  = (const int*)d_in[1];
    const float* W1l = (const float*)d_in[2];
    const float* b1  = (const float*)d_in[3];
    const float* W1r = (const float*)d_in[4];
    const float* g1  = (const float*)d_in[5];
    const float* bt1 = (const float*)d_in[6];
    const float* W2l = (const float*)d_in[7];
    const float* b2  = (const float*)d_in[8];
    const float* W2r = (const float*)d_in[9];
    const float* g2  = (const float*)d_in[10];
    const float* bt2 = (const float*)d_in[11];
    float* out = (float*)d_out;

    const int* esrc = ei;
    const int* edst = ei + N_EDGES;

    char* ws = (char*)d_ws;
    size_t off = 0;
    auto alloc = [&](size_t bytes) { size_t p = off; off = (off + bytes + 255) & ~(size_t)255; return p; };
    float* stats1  = (float*)(ws + alloc(4096 * 4));   // 8 banks x 512 (sum@+col, sumsq@+256+col)
    float* stats2  = (float*)(ws + alloc(4096 * 4));
    int*   bcnt    = (int*)  (ws + alloc(NBKT * 4));
    size_t zero_bytes = off;                       // everything above must be zeroed
    unsigned* bucket = (unsigned*)(ws + alloc((size_t)NBKT * CAP * 4));
    u16*   xh      = (u16*)  (ws + alloc((size_t)N_NODES * DIM * 2));
    u8*    xf8     = (u8*)   (ws + alloc((size_t)N_NODES * DIM));
    u16*   hb1     = (u16*)  (ws + alloc((size_t)N_NODES * DIM * 2));  // raw h1 bf16
    u8*    h1f8    = (u8*)   (ws + alloc((size_t)N_NODES * DIM));     // raw h1 fp8
    u16*   hb2     = (u16*)  (ws + alloc((size_t)N_NODES * DIM * 2));  // raw h2 bf16
    u16*   Bp1h    = (u16*)  (ws + alloc(256 * 128 * 2));
    u16*   Bp2h    = (u16*)  (ws + alloc(256 * 128 * 2));

    hipMemsetAsync(ws, 0, zero_bytes, stream);

    const int AGB = N_NODES / 16;                    // 3125 exact
    const int EWB4 = (int)(((long)N_NODES * DIM) / 1024);  // 6250 exact
    const int EWB8 = (int)(((long)N_NODES * DIM) / 2048);  // 3125 exact
    const int EDGB = N_EDGES / 256;                  // 3125 exact
    const int PREPB = 32 + EWB4 + EDGB;              // pack + split + bucket append

    // prep: pack both B + split x (bf16 + fp8) + single-pass edge bucketing
    k_prep<<<PREPB, 256, 0, stream>>>(W1l, W1r, Bp1h, W2l, W2r, Bp2h, x, xh, xf8,
                                      esrc, edst, bcnt, bucket, EWB4);

    // stage 1: fused agg+gemm on x (fp8 gather, bf16 root); writes h1 bf16 + fp8
    k_ag<0, 1><<<AGB, 512, 0, stream>>>(xf8, xh, bcnt, bucket, Bp1h, b1,
                                        stats1, g1, bt1, hb1, h1f8, stats1);

    // stage 2: fused agg+gemm on h1 with BN+relu at operand load (coeffs from stats1)
    k_ag<1, 0><<<AGB, 512, 0, stream>>>(h1f8, hb1, bcnt, bucket, Bp2h, b2,
                                        stats1, g1, bt1, hb2, h1f8, stats2);

    // epilogue: out = relu(bn(h2) + x), coeffs from stats2
    k_bn_add_relu<<<EWB8, 256, 0, stream>>>(hb2, stats2, g2, bt2, x, out);
}